// Round 1
// baseline (126.662 us; speedup 1.0000x reference)
//
#include <hip/hip_runtime.h>

#define DIM   256
#define NQ    8
#define EMBED 512
#define FFN   2048
#define ROWS  (4 * 8192)             // B*S = 32768
#define OUT_ELEMS (ROWS * EMBED)     // 16777216 fp32
#define OUT_VEC4  (EMBED / 4)        // 128 float4 per row
#define OUT_TOTAL4 (OUT_ELEMS / 4)   // 4194304 float4

// Kernel 1: z from |U[:,0]|^2 marginals, then h = relu(W1 z + b1).
// One block, 256 threads. Writes h (2048 floats) to workspace.
__global__ void k_compute_h(const float* __restrict__ U_re,
                            const float* __restrict__ U_im,
                            const float* __restrict__ W1,
                            const float* __restrict__ b1,
                            float* __restrict__ h) {
    __shared__ float probs[DIM];
    __shared__ float z[NQ];
    int t = threadIdx.x;

    // psi = U[:,0] (column 0, stride DIM); probs[k] = re^2 + im^2
    float re = U_re[t * DIM];
    float im = U_im[t * DIM];
    probs[t] = re * re + im * im;
    __syncthreads();

    // axis i of p.reshape((2,)*8) is bit (7-i) of k (row-major, MSB first)
    if (t < NQ) {
        float s = 0.f;
        int shift = NQ - 1 - t;
        for (int k = 0; k < DIM; ++k) {
            float p = probs[k];
            s += ((k >> shift) & 1) ? -p : p;
        }
        z[t] = s;
    }
    __syncthreads();

    float zr[NQ];
#pragma unroll
    for (int q = 0; q < NQ; ++q) zr[q] = z[q];

#pragma unroll
    for (int r = 0; r < FFN / 256; ++r) {
        int f = r * 256 + t;
        const float4* w = (const float4*)(W1 + f * NQ);  // row f: 8 floats, 32B-aligned
        float4 w0 = w[0], w1 = w[1];
        float acc = b1[f];
        acc += zr[0] * w0.x + zr[1] * w0.y + zr[2] * w0.z + zr[3] * w0.w;
        acc += zr[4] * w1.x + zr[5] * w1.y + zr[6] * w1.z + zr[7] * w1.w;
        h[f] = fmaxf(acc, 0.f);
    }
}

// Kernel 2: out_vec[e] = dot(W2[e,:], h) + b2[e]. One block per e (512 blocks).
// Fully-coalesced float4 reads of the W2 row; tree-reduced fp32 accumulation.
__global__ void k_compute_out(const float* __restrict__ W2,
                              const float* __restrict__ b2,
                              const float* __restrict__ h,
                              float* __restrict__ ov) {
    int e = blockIdx.x;
    int t = threadIdx.x;
    const float4* row = (const float4*)(W2 + (size_t)e * FFN);  // 8KB-aligned
    const float4* h4  = (const float4*)h;

    float4 a0 = row[t],       hb0 = h4[t];
    float4 a1 = row[256 + t], hb1 = h4[256 + t];
    float p = a0.x * hb0.x + a0.y * hb0.y + a0.z * hb0.z + a0.w * hb0.w
            + a1.x * hb1.x + a1.y * hb1.y + a1.z * hb1.z + a1.w * hb1.w;

    // wave(64) shuffle reduction, then LDS across the 4 waves
#pragma unroll
    for (int off = 32; off > 0; off >>= 1)
        p += __shfl_down(p, off, 64);

    __shared__ float wsum[4];
    if ((t & 63) == 0) wsum[t >> 6] = p;
    __syncthreads();
    if (t == 0)
        ov[e] = wsum[0] + wsum[1] + wsum[2] + wsum[3] + b2[e];
}

// Kernel 3: broadcast out_vec (512 floats) to all 32768 rows.
// Grid stride = 2048*256 threads; stride % 128 == 0 so each thread's
// column (idx & 127) is invariant -> load ov once, store 8 float4s.
__global__ void k_broadcast(const float* __restrict__ ov,
                            float* __restrict__ out) {
    const float4* ov4 = (const float4*)ov;
    float4* out4 = (float4*)out;
    int idx = blockIdx.x * blockDim.x + threadIdx.x;
    int stride = gridDim.x * blockDim.x;
    float4 v = ov4[idx & (OUT_VEC4 - 1)];
    for (; idx < OUT_TOTAL4; idx += stride)
        out4[idx] = v;
}

extern "C" void kernel_launch(void* const* d_in, const int* in_sizes, int n_in,
                              void* d_out, int out_size, void* d_ws, size_t ws_size,
                              hipStream_t stream) {
    // inputs: x, U_re, U_im, W1, b1, W2, b2  (x is shape-only, unused)
    const float* U_re = (const float*)d_in[1];
    const float* U_im = (const float*)d_in[2];
    const float* W1   = (const float*)d_in[3];
    const float* b1   = (const float*)d_in[4];
    const float* W2   = (const float*)d_in[5];
    const float* b2   = (const float*)d_in[6];
    float* out = (float*)d_out;

    float* h  = (float*)d_ws;   // 2048 floats
    float* ov = h + FFN;        // 512 floats (16B-aligned: 8192B offset)

    k_compute_h  <<<1,     256, 0, stream>>>(U_re, U_im, W1, b1, h);
    k_compute_out<<<EMBED, 256, 0, stream>>>(W2, b2, h, ov);
    k_broadcast  <<<2048,  256, 0, stream>>>(ov, out);
}

// Round 2
// 120.754 us; speedup vs baseline: 1.0489x; 1.0489x over previous
//
#include <hip/hip_runtime.h>

#define DIM   256
#define NQ    8
#define EMBED 512
#define FFN   2048
#define ROWS  (4 * 8192)             // B*S = 32768
#define OUT_ELEMS (ROWS * EMBED)     // 16777216 fp32
#define OUT_VEC4  (EMBED / 4)        // 128 float4 per row
#define OUT_TOTAL4 (OUT_ELEMS / 4)   // 4194304 float4

// Kernel A: one block per output embedding e (512 blocks, 256 threads).
// Each block REDUNDANTLY computes z (from |U[:,0]|^2 marginals) and
// h = relu(W1 z + b1) — 16K MACs, W1/U reads are L2 hits after the first
// block touches them — then computes ov[e] = dot(W2[e,:], h) + b2[e].
__global__ void k_ov(const float* __restrict__ U_re,
                     const float* __restrict__ U_im,
                     const float* __restrict__ W1,
                     const float* __restrict__ b1,
                     const float* __restrict__ W2,
                     const float* __restrict__ b2,
                     float* __restrict__ ov) {
    int t = threadIdx.x;
    int e = blockIdx.x;

    // ---- probs for this thread's basis state k = t ----
    float re = U_re[t * DIM];     // column 0, stride DIM
    float im = U_im[t * DIM];
    float p  = re * re + im * im;

    // ---- z[q] = sum_k sign(bit(7-q) of k) * p[k], block-parallel ----
    float zp[NQ];
#pragma unroll
    for (int q = 0; q < NQ; ++q)
        zp[q] = ((t >> (NQ - 1 - q)) & 1) ? -p : p;
#pragma unroll
    for (int off = 32; off > 0; off >>= 1) {
#pragma unroll
        for (int q = 0; q < NQ; ++q)
            zp[q] += __shfl_down(zp[q], off, 64);
    }
    __shared__ float zw[4][NQ];
    if ((t & 63) == 0) {
#pragma unroll
        for (int q = 0; q < NQ; ++q) zw[t >> 6][q] = zp[q];
    }
    __syncthreads();
    __shared__ float zs[NQ];
    if (t < NQ) zs[t] = zw[0][t] + zw[1][t] + zw[2][t] + zw[3][t];
    __syncthreads();

    float zr[NQ];
#pragma unroll
    for (int q = 0; q < NQ; ++q) zr[q] = zs[q];

    // ---- h = relu(W1 z + b1) into LDS (each thread does 8 rows) ----
    __shared__ float h[FFN];
#pragma unroll
    for (int r = 0; r < FFN / 256; ++r) {
        int f = r * 256 + t;
        const float4* w = (const float4*)(W1 + f * NQ);  // 32B-aligned row
        float4 w0 = w[0], w1 = w[1];
        float acc = b1[f];
        acc += zr[0] * w0.x + zr[1] * w0.y + zr[2] * w0.z + zr[3] * w0.w;
        acc += zr[4] * w1.x + zr[5] * w1.y + zr[6] * w1.z + zr[7] * w1.w;
        h[f] = fmaxf(acc, 0.f);
    }
    __syncthreads();

    // ---- ov[e] = dot(W2[e,:], h) + b2[e] ----
    const float4* row = (const float4*)(W2 + (size_t)e * FFN);  // 8KB stride
    const float4* h4  = (const float4*)h;
    float4 a0 = row[t],       hb0 = h4[t];
    float4 a1 = row[256 + t], hb1 = h4[256 + t];
    float acc = a0.x * hb0.x + a0.y * hb0.y + a0.z * hb0.z + a0.w * hb0.w
              + a1.x * hb1.x + a1.y * hb1.y + a1.z * hb1.z + a1.w * hb1.w;
#pragma unroll
    for (int off = 32; off > 0; off >>= 1)
        acc += __shfl_down(acc, off, 64);
    __shared__ float wsum[4];
    if ((t & 63) == 0) wsum[t >> 6] = acc;
    __syncthreads();
    if (t == 0)
        ov[e] = wsum[0] + wsum[1] + wsum[2] + wsum[3] + b2[e];
}

// Kernel B: broadcast ov (512 floats) to all 32768 rows of out.
// stride % 128 == 0 -> each thread's column (idx & 127) is invariant:
// load ov once, store 4 float4s, fully coalesced.
__global__ void k_broadcast(const float* __restrict__ ov,
                            float* __restrict__ out) {
    const float4* ov4 = (const float4*)ov;
    float4* out4 = (float4*)out;
    int idx = blockIdx.x * blockDim.x + threadIdx.x;
    int stride = gridDim.x * blockDim.x;   // 4096*256 = 1048576, %128==0
    float4 v = ov4[idx & (OUT_VEC4 - 1)];
    for (; idx < OUT_TOTAL4; idx += stride)
        out4[idx] = v;
}

extern "C" void kernel_launch(void* const* d_in, const int* in_sizes, int n_in,
                              void* d_out, int out_size, void* d_ws, size_t ws_size,
                              hipStream_t stream) {
    // inputs: x, U_re, U_im, W1, b1, W2, b2  (x is shape-only, unused)
    const float* U_re = (const float*)d_in[1];
    const float* U_im = (const float*)d_in[2];
    const float* W1   = (const float*)d_in[3];
    const float* b1   = (const float*)d_in[4];
    const float* W2   = (const float*)d_in[5];
    const float* b2   = (const float*)d_in[6];
    float* out = (float*)d_out;

    float* ov = (float*)d_ws;    // 512 floats of scratch

    k_ov       <<<EMBED, 256, 0, stream>>>(U_re, U_im, W1, b1, W2, b2, ov);
    k_broadcast<<<4096,  256, 0, stream>>>(ov, out);
}